// Round 13
// baseline (1271.337 us; speedup 1.0000x reference)
//
#include <hip/hip_runtime.h>

#define NN 200000
#define EE 800000
#define GG 2048
#define NBLK ((NN + 255) / 256)   // 782

typedef __attribute__((ext_vector_type(8))) short short8;
typedef __attribute__((ext_vector_type(4))) float f32x4;

__device__ __forceinline__ float bf2f(ushort u){
  unsigned x = ((unsigned)u) << 16;
  return __uint_as_float(x);
}
__device__ __forceinline__ ushort f2bf(float f){
  unsigned x = __float_as_uint(f);
  x += 0x7fffu + ((x >> 16) & 1u);
  return (ushort)(x >> 16);
}
// swizzled ZT address: 16B granule G=c>>3 placed at G^(r&7); row stride 256 ushorts
__device__ __forceinline__ int ztAddr(int r, int c){
  return r*256 + (((c >> 3) ^ (r & 7)) << 3) + (c & 7);
}

// swizzle a 256xK fp32 weight into MFMA B-fragment order (K=256)
__device__ __forceinline__ void swz256(const float* __restrict__ W, ushort* __restrict__ o, int idx){
  int ks = idx >> 13, rem = idx & 8191;
  int j16 = rem >> 9, rem2 = rem & 511;
  int ln = rem2 >> 3, t = rem2 & 7;
  int row = j16*16 + (ln & 15);
  int k = ks*32 + (ln >> 4)*8 + t;
  o[idx] = f2bf(W[(size_t)row*256 + k]);
}

// ---------------- prep: weight conversion/swizzle + edge-bias tables ----------------
__global__ __launch_bounds__(256) void prep_k(
    const float* __restrict__ W10, const float* __restrict__ W20,
    const float* __restrict__ W11, const float* __restrict__ W21,
    const float* __restrict__ W12, const float* __restrict__ W22,
    const float* __restrict__ lw0, const float* __restrict__ lb0,
    const float* __restrict__ lw1, const float* __restrict__ lb1,
    const float* __restrict__ lw2, const float* __restrict__ lb2,
    const float* __restrict__ eE, const float* __restrict__ mW1,
    const float* __restrict__ mW2,
    ushort* __restrict__ wb10, ushort* __restrict__ wb20,
    ushort* __restrict__ wb11, ushort* __restrict__ wb21,
    ushort* __restrict__ wb12, ushort* __restrict__ wb22,
    ushort* __restrict__ mW1b, ushort* __restrict__ mW2b,
    float* __restrict__ eb)
{
  int b = blockIdx.x, tid = threadIdx.x;
  if (b < 64){ // W1_0 (256x44) -> B-frag swizzled 256x64 (2 kslices), zero-padded
    int idx = b*256 + tid;
    int ks = idx >> 13, rem = idx & 8191;
    int j16 = rem >> 9, rem2 = rem & 511;
    int ln = rem2 >> 3, t = rem2 & 7;
    int row = j16*16 + (ln & 15);
    int k = ks*32 + (ln >> 4)*8 + t;
    wb10[idx] = (k < 44) ? f2bf(W10[row*44 + k]) : (ushort)0;
    return;
  }
  b -= 64;
  if (b < 256){ swz256(W20, wb20, b*256+tid); return; } b -= 256;
  if (b < 256){ swz256(W11, wb11, b*256+tid); return; } b -= 256;
  if (b < 256){ swz256(W21, wb21, b*256+tid); return; } b -= 256;
  if (b < 256){ swz256(W12, wb12, b*256+tid); return; } b -= 256;
  if (b < 256){ swz256(W22, wb22, b*256+tid); return; } b -= 256;
  if (b < 384){ // mW1 (256x323) -> padded row-major (256x384)
    int idx = b*256 + tid; int o = idx / 384, k = idx - o*384;
    mW1b[idx] = (k < 323) ? f2bf(mW1[(size_t)o*323 + k]) : (ushort)0;
    return;
  }
  b -= 384;
  if (b < 512){ int idx = b*256+tid; mW2b[idx] = f2bf(mW2[idx]); return; } b -= 512;
  int li = b >> 2, t = b & 3;
  const float* lw = (li == 0) ? lw0 : ((li == 1) ? lw1 : lw2);
  const float* lb = (li == 0) ? lb0 : ((li == 1) ? lb1 : lb2);
  int d = (li == 0) ? 44 : 256;
  float v = 0.f;
  if (tid < d){
    float a = 0.f;
    #pragma unroll
    for (int j = 0; j < 16; j++) a += eE[t*16 + j] * lw[tid*16 + j];
    v = a + lb[tid];
  }
  eb[(li*4 + t)*256 + tid] = v;
}

// ---------------- h0 = [op_embed[op], nums, 0-pad] as bf16 N x 64 ----------------
__global__ __launch_bounds__(256) void build_h0_k(
    const float* __restrict__ x, const float* __restrict__ opE, ushort* __restrict__ h0)
{
  int idx = blockIdx.x*256 + threadIdx.x;
  int i = idx >> 6, c = idx & 63;
  float v = 0.f;
  if (c < 32){
    int op = (int)x[(size_t)i*13];
    op = op < 0 ? 0 : (op > 63 ? 63 : op);
    v = opE[op*32 + c];
  } else if (c < 44){
    v = x[(size_t)i*13 + (c - 31)];
  }
  h0[idx] = f2bf(v);
}

// ================= CSR build =================
__global__ __launch_bounds__(256) void deg_k(const int* __restrict__ dst, int* __restrict__ D){
  int e = blockIdx.x*256 + threadIdx.x;
  atomicAdd(&D[dst[e]], 1);
}
__global__ __launch_bounds__(256) void scan1_k(int* __restrict__ D, int* __restrict__ bsum){
  __shared__ int s[256];
  int b = blockIdx.x, t = threadIdx.x, idx = b*256 + t;
  int v = (idx < NN) ? D[idx] : 0;
  s[t] = v; __syncthreads();
  for (int off = 1; off < 256; off <<= 1){
    int u = (t >= off) ? s[t-off] : 0;
    __syncthreads();
    s[t] += u;
    __syncthreads();
  }
  if (idx < NN) D[idx] = s[t] - v;
  if (t == 255) bsum[b] = s[255];
}
__global__ __launch_bounds__(256) void scan2_k(int* __restrict__ bsum){
  __shared__ int s[256];
  __shared__ int carry;
  int t = threadIdx.x;
  if (t == 0) carry = 0;
  __syncthreads();
  for (int c0 = 0; c0 < NBLK; c0 += 256){
    int idx = c0 + t;
    int v = (idx < NBLK) ? bsum[idx] : 0;
    s[t] = v; __syncthreads();
    for (int off = 1; off < 256; off <<= 1){
      int u = (t >= off) ? s[t-off] : 0;
      __syncthreads();
      s[t] += u;
      __syncthreads();
    }
    int ex = s[t] - v + carry;
    if (idx < NBLK) bsum[idx] = ex;
    int tot = s[255];
    __syncthreads();
    if (t == 0) carry += tot;
    __syncthreads();
  }
}
__global__ __launch_bounds__(256) void scan3_k(int* __restrict__ D, const int* __restrict__ bsum){
  int b = blockIdx.x, idx = b*256 + threadIdx.x;
  if (idx < NN) D[idx] += bsum[b];
}
__global__ __launch_bounds__(256) void fill_k(const int* __restrict__ src, const int* __restrict__ dst,
                                              const int* __restrict__ et, int* __restrict__ D,
                                              int* __restrict__ csr){
  int e = blockIdx.x*256 + threadIdx.x;
  int d = dst[e];
  int t = et[e]; t = t < 3 ? t : 3;
  int pos = atomicAdd(&D[d], 1);
  csr[pos] = src[e] | (t << 18);
}

// ---------------- fused layer: flat-edge-walk gather + MLP + LN, swizzled ZT ----------------
// 32 rows/block, grid 6250. Phase A: each wave walks the contiguous CSR range of its
// 8 rows edge-by-edge (whole wave per edge), 4-slot prefetch, scalar control.
template<int KD, int RESID>
__global__ __launch_bounds__(256) void layerf_k(
    const ushort* __restrict__ hsrc, const int* __restrict__ Dend, const int* __restrict__ csr,
    const float* __restrict__ ebL,
    const ushort* __restrict__ W1s, const float* __restrict__ b1,
    const ushort* __restrict__ W2s, const float* __restrict__ b2,
    const float* __restrict__ epsp, ushort* __restrict__ hout)
{
  __shared__ ushort ZT[32*256];            // swizzled (16B granule ^ (r&7))
  __shared__ float ebs[1024];
  __shared__ float red1[32][4], red2[32][4], mnL[32], rsL[32];
  const int tid = threadIdx.x, lane = tid & 63, wv = tid >> 6;
  const int l15 = lane & 15, lq = lane >> 4;
  const int rowBase = blockIdx.x * 32;
  const float epv = 1.0f + epsp[0];
  const char* hb = (const char*)hsrc;

  if (KD == 256){
    for (int i = tid; i < 1024; i += 256) ebs[i] = ebL[i];
  } else {
    if (tid < 256) ebs[tid] = ebL[(tid >> 6)*256 + (tid & 63)];  // compact [4][64]
  }
  __syncthreads();

  // ---- A: z = (1+eps)h[r] + sum_e relu(h[src]+eb[et]) -> ZT (swizzled) ----
  if (KD == 256){
    const int c = lane * 4;
    const unsigned cb = lane * 8;   // byte offset within a 512B row
    const int rBase8 = wv*8;        // block-local row base for this wave
    const int r0 = rowBase + rBase8;
    const int end0 = Dend[r0+0], end1 = Dend[r0+1], end2 = Dend[r0+2], end3 = Dend[r0+3];
    const int end4 = Dend[r0+4], end5 = Dend[r0+5], end6 = Dend[r0+6], end7 = Dend[r0+7];
    int e = (r0 == 0) ? 0 : Dend[r0-1];
    const int eEnd = end7;
    int rr = 0;
    int ebound = end0;
    ushort4 hnext = *(const ushort4*)(hb + (size_t)(r0+1)*512 + cb);
    int rowPf = 2;
    float4 acc;
    {
      ushort4 hcur = *(const ushort4*)(hb + (size_t)r0*512 + cb);
      acc = make_float4(epv*bf2f(hcur.x), epv*bf2f(hcur.y), epv*bf2f(hcur.z), epv*bf2f(hcur.w));
    }
    ushort4 sv0, sv1, sv2, sv3;
    int t0 = 0, t1 = 0, t2 = 0, t3 = 0;
    sv0.x=sv0.y=sv0.z=sv0.w=0; sv1=sv0; sv2=sv0; sv3=sv0;
    if (e+0 < eEnd){ int p = csr[e+0]; sv0 = *(const ushort4*)(hb + (unsigned)((p & 0x3FFFF) << 9) + cb); t0 = ((p >> 18) & 3)*256; }
    if (e+1 < eEnd){ int p = csr[e+1]; sv1 = *(const ushort4*)(hb + (unsigned)((p & 0x3FFFF) << 9) + cb); t1 = ((p >> 18) & 3)*256; }
    if (e+2 < eEnd){ int p = csr[e+2]; sv2 = *(const ushort4*)(hb + (unsigned)((p & 0x3FFFF) << 9) + cb); t2 = ((p >> 18) & 3)*256; }
    if (e+3 < eEnd){ int p = csr[e+3]; sv3 = *(const ushort4*)(hb + (unsigned)((p & 0x3FFFF) << 9) + cb); t3 = ((p >> 18) & 3)*256; }

    auto flushTo = [&](int ee){
      while (ee >= ebound){
        ushort4 o; o.x = f2bf(acc.x); o.y = f2bf(acc.y); o.z = f2bf(acc.z); o.w = f2bf(acc.w);
        *(ushort4*)(ZT + ztAddr(rBase8 + rr, c)) = o;     // FIX: block-local row
        rr++;
        acc = make_float4(epv*bf2f(hnext.x), epv*bf2f(hnext.y), epv*bf2f(hnext.z), epv*bf2f(hnext.w));
        if (rowPf < 8){ hnext = *(const ushort4*)(hb + (size_t)(r0+rowPf)*512 + cb); rowPf++; }
        ebound = (rr==1)?end1:(rr==2)?end2:(rr==3)?end3:(rr==4)?end4:(rr==5)?end5:(rr==6)?end6:end7;
      }
    };
    auto consume = [&](const ushort4 s, int t){
      const float4 ev = *(const float4*)&ebs[t + c];
      float v;
      v = bf2f(s.x) + ev.x; acc.x += v > 0.f ? v : 0.f;
      v = bf2f(s.y) + ev.y; acc.y += v > 0.f ? v : 0.f;
      v = bf2f(s.z) + ev.z; acc.z += v > 0.f ? v : 0.f;
      v = bf2f(s.w) + ev.w; acc.w += v > 0.f ? v : 0.f;
    };

    for (int eb2 = e; eb2 < eEnd; eb2 += 4){
      {
        int ee = eb2;
        flushTo(ee); consume(sv0, t0);
        if (ee+4 < eEnd){ int p = csr[ee+4]; sv0 = *(const ushort4*)(hb + (unsigned)((p & 0x3FFFF) << 9) + cb); t0 = ((p >> 18) & 3)*256; }
      }
      { int ee = eb2+1; if (ee < eEnd){
          flushTo(ee); consume(sv1, t1);
          if (ee+4 < eEnd){ int p = csr[ee+4]; sv1 = *(const ushort4*)(hb + (unsigned)((p & 0x3FFFF) << 9) + cb); t1 = ((p >> 18) & 3)*256; }
      } }
      { int ee = eb2+2; if (ee < eEnd){
          flushTo(ee); consume(sv2, t2);
          if (ee+4 < eEnd){ int p = csr[ee+4]; sv2 = *(const ushort4*)(hb + (unsigned)((p & 0x3FFFF) << 9) + cb); t2 = ((p >> 18) & 3)*256; }
      } }
      { int ee = eb2+3; if (ee < eEnd){
          flushTo(ee); consume(sv3, t3);
          if (ee+4 < eEnd){ int p = csr[ee+4]; sv3 = *(const ushort4*)(hb + (unsigned)((p & 0x3FFFF) << 9) + cb); t3 = ((p >> 18) & 3)*256; }
      } }
    }
    // tail: flush rows rr..7
    for (;;){
      ushort4 o; o.x = f2bf(acc.x); o.y = f2bf(acc.y); o.z = f2bf(acc.z); o.w = f2bf(acc.w);
      *(ushort4*)(ZT + ztAddr(rBase8 + rr, c)) = o;       // FIX: block-local row
      if (rr == 7) break;
      rr++;
      acc = make_float4(epv*bf2f(hnext.x), epv*bf2f(hnext.y), epv*bf2f(hnext.z), epv*bf2f(hnext.w));
      if (rowPf < 8){ hnext = *(const ushort4*)(hb + (size_t)(r0+rowPf)*512 + cb); rowPf++; }
    }
  } else {
    const int c = l15 * 4;
    const unsigned c2 = l15 * 8;
    #pragma unroll 1
    for (int it = 0; it < 2; it++){
      int rr = wv*8 + it*4 + lq;
      int r = rowBase + rr;
      const ushort4 hv = *(const ushort4*)(hb + (size_t)r*128 + c2);
      float a0 = epv*bf2f(hv.x), a1 = epv*bf2f(hv.y), a2 = epv*bf2f(hv.z), a3 = epv*bf2f(hv.w);
      int st = (r == 0) ? 0 : Dend[r-1];
      int en = Dend[r];
      if (st < en){
        int p = csr[st];
        ushort4 sv = *(const ushort4*)(hb + (unsigned)((p & 0x3FFFF) << 7) + c2);
        int tt = ((p >> 18) & 3)*64;
        for (int e = st; e < en; e++){
          ushort4 cur = sv; int tc = tt;
          int e2 = (e+1 < en) ? e+1 : e;
          int p2 = csr[e2];
          sv = *(const ushort4*)(hb + (unsigned)((p2 & 0x3FFFF) << 7) + c2);
          tt = ((p2 >> 18) & 3)*64;
          const float4 ev = *(const float4*)&ebs[tc + c];
          float v;
          v = bf2f(cur.x) + ev.x; a0 += v > 0.f ? v : 0.f;
          v = bf2f(cur.y) + ev.y; a1 += v > 0.f ? v : 0.f;
          v = bf2f(cur.z) + ev.z; a2 += v > 0.f ? v : 0.f;
          v = bf2f(cur.w) + ev.w; a3 += v > 0.f ? v : 0.f;
        }
      }
      ushort4 o; o.x=f2bf(a0); o.y=f2bf(a1); o.z=f2bf(a2); o.w=f2bf(a3);
      *(ushort4*)(ZT + ztAddr(rr, c)) = o;
    }
  }
  __syncthreads();

  // ---- B: t = relu(z @ W1^T + b1), wave tile 32x64; swizzled fragment reads ----
  f32x4 acc[2][4];
  #pragma unroll
  for (int i = 0; i < 2; i++)
    #pragma unroll
    for (int j = 0; j < 4; j++){ f32x4 z = {0.f,0.f,0.f,0.f}; acc[i][j] = z; }

  #pragma unroll
  for (int s = 0; s < KD/32; s++){
    short8 af[2], bfv[4];
    #pragma unroll
    for (int j = 0; j < 4; j++)
      bfv[j] = *(const short8*)(W1s + ((size_t)(s*16 + wv*4 + j)*64 + lane)*8);
    #pragma unroll
    for (int i = 0; i < 2; i++){
      int row = i*16 + l15;
      af[i] = *(const short8*)(ZT + row*256 + (((s*4 + lq) ^ (l15 & 7)) << 3));
    }
    #pragma unroll
    for (int i = 0; i < 2; i++)
      #pragma unroll
      for (int j = 0; j < 4; j++)
        acc[i][j] = __builtin_amdgcn_mfma_f32_16x16x32_bf16(af[i], bfv[j], acc[i][j], 0, 0, 0);
  }
  __syncthreads();

  // ---- C: t -> ZT (swizzled) ----
  {
    float b1c[4];
    #pragma unroll
    for (int j = 0; j < 4; j++) b1c[j] = b1[wv*64 + j*16 + l15];
    #pragma unroll
    for (int i = 0; i < 2; i++)
      #pragma unroll
      for (int j = 0; j < 4; j++){
        int cc = wv*64 + j*16 + l15;
        #pragma unroll
        for (int rg = 0; rg < 4; rg++){
          int r = i*16 + (lq << 2) + rg;
          float v = acc[i][j][rg] + b1c[j];
          v = v > 0.f ? v : 0.f;
          ZT[ztAddr(r, cc)] = f2bf(v);
        }
      }
  }
  __syncthreads();

  // ---- D: y = t @ W2^T ----
  #pragma unroll
  for (int i = 0; i < 2; i++)
    #pragma unroll
    for (int j = 0; j < 4; j++){ f32x4 z = {0.f,0.f,0.f,0.f}; acc[i][j] = z; }

  #pragma unroll
  for (int s = 0; s < 8; s++){
    short8 af[2], bfv[4];
    #pragma unroll
    for (int j = 0; j < 4; j++)
      bfv[j] = *(const short8*)(W2s + ((size_t)(s*16 + wv*4 + j)*64 + lane)*8);
    #pragma unroll
    for (int i = 0; i < 2; i++){
      int row = i*16 + l15;
      af[i] = *(const short8*)(ZT + row*256 + (((s*4 + lq) ^ (l15 & 7)) << 3));
    }
    #pragma unroll
    for (int i = 0; i < 2; i++)
      #pragma unroll
      for (int j = 0; j < 4; j++)
        acc[i][j] = __builtin_amdgcn_mfma_f32_16x16x32_bf16(af[i], bfv[j], acc[i][j], 0, 0, 0);
  }

  // ---- E: LayerNorm stats ----
  float b2c[4];
  #pragma unroll
  for (int j = 0; j < 4; j++) b2c[j] = b2[wv*64 + j*16 + l15];
  #pragma unroll
  for (int i = 0; i < 2; i++){
    #pragma unroll
    for (int rg = 0; rg < 4; rg++){
      float s1 = 0.f, s2 = 0.f;
      #pragma unroll
      for (int j = 0; j < 4; j++){
        float y = acc[i][j][rg] + b2c[j];
        s1 += y; s2 += y*y;
      }
      #pragma unroll
      for (int m = 1; m < 16; m <<= 1){
        s1 += __shfl_xor(s1, m, 64);
        s2 += __shfl_xor(s2, m, 64);
      }
      if (l15 == 0){
        int r = i*16 + (lq << 2) + rg;
        red1[r][wv] = s1; red2[r][wv] = s2;
      }
    }
  }
  __syncthreads();
  if (tid < 32){
    float s1 = red1[tid][0] + red1[tid][1] + red1[tid][2] + red1[tid][3];
    float s2 = red2[tid][0] + red2[tid][1] + red2[tid][2] + red2[tid][3];
    float mn = s1 * (1.f/256.f);
    float vr = s2 * (1.f/256.f) - mn*mn;
    mnL[tid] = mn;
    rsL[tid] = rsqrtf(vr + 1e-5f);
  }
  __syncthreads();
  // ---- F: LN + resid (global re-read, L2/L3-hot) + leaky -> ZT ----
  #pragma unroll
  for (int i = 0; i < 2; i++){
    #pragma unroll
    for (int rg = 0; rg < 4; rg++){
      int r = i*16 + (lq << 2) + rg;
      float mn = mnL[r], rs = rsL[r];
      #pragma unroll
      for (int j = 0; j < 4; j++){
        int cc = wv*64 + j*16 + l15;
        float y = acc[i][j][rg] + b2c[j];
        float v = (y - mn) * rs;
        if (RESID) v += bf2f(hsrc[(size_t)(rowBase + r)*256 + cc]);
        v = v > 0.f ? v : 0.1f*v;
        ZT[ztAddr(r, cc)] = f2bf(v);
      }
    }
  }
  __syncthreads();
  // ---- G: coalesced store (swizzled read) ----
  #pragma unroll
  for (int p = 0; p < 8; p++){
    int r = p*4 + (tid >> 6);
    int c = (tid & 63) * 4;
    *(ushort4*)(hout + (size_t)(rowBase + r)*256 + c) = *(const ushort4*)(ZT + ztAddr(r, c));
  }
}

// ---------------- readout -> catb bf16 (G x 384); row-parallel waves ----------------
__global__ __launch_bounds__(256) void readout_k(
    const ushort* __restrict__ h, const int* __restrict__ batch, const float* __restrict__ x,
    const int* __restrict__ sqlIds, const float* __restrict__ sqlMask,
    const float* __restrict__ tok, ushort* __restrict__ catb)
{
  int g = blockIdx.x, tid = threadIdx.x;
  const int lane = tid & 63, wv = tid >> 6;
  __shared__ int se[2];
  __shared__ float part[4][256];
  __shared__ float tpart[4][64];
  __shared__ float mpart[4];
  __shared__ float xs[2];
  if (tid < 2){
    int target = g + tid;
    int lo = 0, hi = NN;
    while (lo < hi){ int mid = (lo + hi) >> 1; if (batch[mid] < target) lo = mid + 1; else hi = mid; }
    se[tid] = lo;
  }
  __syncthreads();
  int start = se[0], end = se[1];
  {
    float a0 = 0.f, a1 = 0.f, a2 = 0.f, a3 = 0.f;
    for (int i = start + wv; i < end; i += 4){
      ushort4 q = *(const ushort4*)(h + (size_t)i*256 + lane*4);
      a0 += bf2f(q.x); a1 += bf2f(q.y); a2 += bf2f(q.z); a3 += bf2f(q.w);
    }
    part[wv][lane*4 + 0] = a0;
    part[wv][lane*4 + 1] = a1;
    part[wv][lane*4 + 2] = a2;
    part[wv][lane*4 + 3] = a3;
  }
  if (wv >= 2){
    int col = (wv == 2) ? 5 : 4;
    float s = 0.f;
    for (int i = start + lane; i < end; i += 64) s += x[(size_t)i*13 + col];
    #pragma unroll
    for (int m = 1; m < 64; m <<= 1) s += __shfl_xor(s, m, 64);
    if (lane == 0) xs[wv - 2] = s;
  }
  {
    int c = lane;
    float acc = 0.f, m = 0.f;
    for (int s = wv; s < 128; s += 4){
      int id = sqlIds[g*128 + s];
      float mk = sqlMask[g*128 + s];
      m += mk;
      acc += tok[(size_t)id*64 + c] * mk;
    }
    tpart[wv][c] = acc;
    if (c == 0) mpart[wv] = m;
  }
  __syncthreads();
  {
    float gsum = part[0][tid] + part[1][tid] + part[2][tid] + part[3][tid];
    catb[(size_t)g*384 + tid] = f2bf(gsum);
  }
  if (tid == 0){
    float cnt = (float)(end - start);
    float dn = cnt > 1.f ? cnt : 1.f;
    catb[(size_t)g*384 + 256] = f2bf(cnt);
    catb[(size_t)g*384 + 257] = f2bf(xs[0] / dn);
    catb[(size_t)g*384 + 258] = f2bf(xs[1] / dn);
  }
  if (tid < 64){
    float L = mpart[0] + mpart[1] + mpart[2] + mpart[3];
    L = L > 1.f ? L : 1.f;
    float tsum = tpart[0][tid] + tpart[1][tid] + tpart[2][tid] + tpart[3][tid];
    catb[(size_t)g*384 + 259 + tid] = f2bf(tsum / L);
  }
  if (tid >= 64 && tid < 125){
    catb[(size_t)g*384 + 259 + tid] = 0;   // zero pad 323..383
  }
}

// ---------------- head GEMM1: hid = leaky(catb @ mW1b^T + mb1), bf16 out ----------------
__global__ __launch_bounds__(256) void head1_k(
    const ushort* __restrict__ catb, const ushort* __restrict__ W1b,
    const float* __restrict__ b1, ushort* __restrict__ hidb)
{
  __shared__ ushort smem[64*72 + 256*72];
  ushort (*As)[72] = (ushort(*)[72])smem;
  ushort (*Ws)[72] = (ushort(*)[72])(smem + 64*72);
  const int tid = threadIdx.x, lane = tid & 63, wv = tid >> 6;
  const int rowBase = blockIdx.x * 64;
  f32x4 acc[4][4];
  #pragma unroll
  for (int i = 0; i < 4; i++)
    #pragma unroll
    for (int j = 0; j < 4; j++){ f32x4 z = {0.f,0.f,0.f,0.f}; acc[i][j] = z; }

  for (int k0 = 0; k0 < 384; k0 += 64){
    __syncthreads();
    #pragma unroll
    for (int p = 0; p < 4; p++){
      int r = p*16 + (tid >> 4);
      int kk = (tid & 15) * 4;
      *(ushort4*)&As[r][kk] = *(const ushort4*)(catb + (size_t)(rowBase + r)*384 + k0 + kk);
    }
    #pragma unroll
    for (int p = 0; p < 16; p++){
      int oc = p*16 + (tid >> 4);
      int kk = (tid & 15) * 4;
      *(ushort4*)&Ws[oc][kk] = *(const ushort4*)(W1b + (size_t)oc*384 + k0 + kk);
    }
    __syncthreads();
    #pragma unroll
    for (int kc = 0; kc < 2; kc++){
      short8 af[4], bfv[4];
      #pragma unroll
      for (int i = 0; i < 4; i++)
        af[i] = *(const short8*)&As[i*16 + (lane & 15)][kc*32 + (lane >> 4)*8];
      #pragma unroll
      for (int j = 0; j < 4; j++)
        bfv[j] = *(const short8*)&Ws[wv*64 + j*16 + (lane & 15)][kc*32 + (lane >> 4)*8];
      #pragma unroll
      for (int i = 0; i < 4; i++)
        #pragma unroll
        for (int j = 0; j < 4; j++)
          acc[i][j] = __builtin_amdgcn_mfma_f32_16x16x32_bf16(af[i], bfv[j], acc[i][j], 0, 0, 0);
    }
  }
  __syncthreads();
  ushort (*Cs)[264] = (ushort(*)[264])smem;
  #pragma unroll
  for (int j = 0; j < 4; j++){
    int cc = wv*64 + j*16 + (lane & 15);
    float bb = b1[cc];
    #pragma unroll
    for (int i = 0; i < 4; i++){
      #pragma unroll
      for (int rg = 0; rg < 4; rg++){
        int r = i*16 + ((lane >> 4) << 2) + rg;
        float v = acc[i][j][rg] + bb;
        v = v > 0.f ? v : 0.1f*v;
        Cs[r][cc] = f2bf(v);
      }
    }
  }
  __syncthreads();
  #pragma unroll
  for (int p = 0; p < 16; p++){
    int r = p*4 + (tid >> 6);
    int c = (tid & 63) * 4;
    *(ushort4*)(hidb + (size_t)(rowBase + r)*256 + c) = *(const ushort4*)&Cs[r][c];
  }
}

// ---------------- head GEMM2: out = hidb @ mW2b^T + mb2, fp32 out ----------------
__global__ __launch_bounds__(256) void head2_k(
    const ushort* __restrict__ hidb, const ushort* __restrict__ W2b,
    const float* __restrict__ b2, float* __restrict__ out)
{
  __shared__ float smemf[128*132];
  ushort (*As)[72] = (ushort(*)[72])smemf;
  ushort (*Bs)[72] = (ushort(*)[72])((ushort*)smemf + 128*72);
  const int tid = threadIdx.x, lane = tid & 63, wv = tid >> 6;
  const int wr = (wv >> 1) * 64;
  const int wc = (wv & 1) * 64;
  const int rowBase = blockIdx.x * 128;
  const int colBase = blockIdx.y * 128;
  const int lr = tid >> 4, lk = (tid & 15) * 4;

  f32x4 acc[4][4];
  #pragma unroll
  for (int i = 0; i < 4; i++)
    #pragma unroll
    for (int j = 0; j < 4; j++){ f32x4 z = {0.f,0.f,0.f,0.f}; acc[i][j] = z; }

  for (int k0 = 0; k0 < 256; k0 += 64){
    __syncthreads();
    #pragma unroll
    for (int p = 0; p < 8; p++){
      int r = lr + p*16;
      *(ushort4*)&As[r][lk] = *(const ushort4*)(hidb + (size_t)(rowBase + r)*256 + k0 + lk);
      *(ushort4*)&Bs[r][lk] = *(const ushort4*)(W2b + (size_t)(colBase + r)*256 + k0 + lk);
    }
    __syncthreads();
    #pragma unroll
    for (int kc = 0; kc < 2; kc++){
      short8 af[4], bfv[4];
      #pragma unroll
      for (int i = 0; i < 4; i++)
        af[i] = *(const short8*)&As[wr + i*16 + (lane & 15)][kc*32 + (lane >> 4)*8];
      #pragma unroll
      for (int j = 0; j < 4; j++)
        bfv[j] = *(const short8*)&Bs[wc + j*16 + (lane & 15)][kc*32 + (lane >> 4)*8];
      #pragma unroll
      for (int i = 0; i < 4; i++)
        #pragma unroll
        for (int j = 0; j < 4; j++)
          acc[i][j] = __builtin_amdgcn_mfma_f32_16x16x32_bf16(af[i], bfv[j], acc[i][j], 0, 0, 0);
    }
  }
  __syncthreads();
  float (*Cs)[132] = (float(*)[132])smemf;
  #pragma unroll
  for (int j = 0; j < 4; j++){
    int cl = wc + j*16 + (lane & 15);
    float bb = b2[colBase + cl];
    #pragma unroll
    for (int i = 0; i < 4; i++){
      int r0 = wr + i*16 + ((lane >> 4) << 2);
      #pragma unroll
      for (int rg = 0; rg < 4; rg++)
        Cs[r0 + rg][cl] = acc[i][j][rg] + bb;
    }
  }
  __syncthreads();
  #pragma unroll
  for (int p = 0; p < 16; p++){
    int r = (tid >> 5) + p*8;
    int c4 = (tid & 31) * 4;
    *(float4*)(out + (size_t)(rowBase + r)*512 + colBase + c4) = *(const float4*)&Cs[r][c4];
  }
}

extern "C" void kernel_launch(void* const* d_in, const int* in_sizes, int n_in,
                              void* d_out, int out_size, void* d_ws, size_t ws_size,
                              hipStream_t stream)
{
  const float* x       = (const float*)d_in[0];
  const int*   ei      = (const int*)d_in[1];
  const int*   src     = ei;
  const int*   dst     = ei + EE;
  const int*   eattr   = (const int*)d_in[2];
  const int*   batch   = (const int*)d_in[3];
  const int*   sqlIds  = (const int*)d_in[4];
  const float* sqlMask = (const float*)d_in[5];
  const float* opE     = (const float*)d_in[6];
  const float* eE      = (const float*)d_in[7];
  const float* tok     = (const float*)d_in[8];
  const float* lw0 = (const float*)d_in[9],  *lb0 = (const float*)d_in[10], *eps0 = (const float*)d_in[11];
  const float* W10 = (const float*)d_in[12], *b10 = (const float*)d_in[13];
  const float* W20 = (const float*)d_in[14], *b20 = (const float*)d_in[15];
  const float* lw1 = (const float*)d_in[16], *lb1 = (const float*)d_in[17], *eps1 = (const float*)d_in[18];
  const float* W11 = (const float*)d_in[19], *b11 = (const float*)d_in[20];
  const float* W21 = (const float*)d_in[21], *b21 = (const float*)d_in[22];
  const float* lw2 = (const float*)d_in[23], *lb2 = (const float*)d_in[24], *eps2 = (const float*)d_in[25];
  const float* W12 = (const float*)d_in[26], *b12 = (const float*)d_in[27];
  const float* W22 = (const float*)d_in[28], *b22 = (const float*)d_in[29];
  const float* mW1 = (const float*)d_in[30], *mb1 = (const float*)d_in[31];
  const float* mW2 = (const float*)d_in[32], *mb2 = (const float*)d_in[33];
  float* out = (float*)d_out;

  // ---- workspace layout (same footprint as R11) ----
  char* ws = (char*)d_ws;
  size_t off = 0;
  const size_t NB256 = (size_t)NN*256*2;
  ushort* bufH    = (ushort*)(ws + off); off += NB256;   // h ping buffer
  char*   region  = ws + off;            off += NB256;   // h0 / h pong buffer / catb+hidb
  ushort* h0      = (ushort*)region;
  ushort* hPong   = (ushort*)region;
  ushort* catb    = (ushort*)region;
  ushort* hidb    = (ushort*)(region + (size_t)GG*384*2);
  ushort* wb10 = (ushort*)(ws + off); off += (size_t)256*64*2;
  ushort* wb20 = (ushort*)(ws + off); off += (size_t)65536*2;
  ushort* wb11 = (ushort*)(ws + off); off += (size_t)65536*2;
  ushort* wb21 = (ushort*)(ws + off); off += (size_t)65536*2;
  ushort* wb12 = (ushort*)(ws + off); off += (size_t)65536*2;
  ushort* wb22 = (ushort*)(ws + off); off += (size_t)65536*2;
  ushort* mW1b = (ushort*)(ws + off); off += (size_t)256*384*2;
  ushort* mW2b = (ushort*)(ws + off); off += (size_t)512*256*2;
  float*  eb   = (float*)(ws + off);  off += (size_t)3*4*256*4;
  int* D    = (int*)(ws + off); off += (size_t)NN*4;
  int* bsum = (int*)(ws + off); off += (size_t)NBLK*4;
  int* csr  = (int*)(ws + off); off += (size_t)EE*4;
  size_t needFast = off;

  if (ws_size < needFast) return;

  prep_k<<<2252, 256, 0, stream>>>(W10, W20, W11, W21, W12, W22,
                                   lw0, lb0, lw1, lb1, lw2, lb2, eE, mW1, mW2,
                                   wb10, wb20, wb11, wb21, wb12, wb22, mW1b, mW2b, eb);
  build_h0_k<<<50000, 256, 0, stream>>>(x, opE, h0);

  // ---- CSR build (by dst) ----
  hipMemsetAsync(D, 0, (size_t)NN*4, stream);
  deg_k<<<3125, 256, 0, stream>>>(dst, D);
  scan1_k<<<NBLK, 256, 0, stream>>>(D, bsum);
  scan2_k<<<1, 256, 0, stream>>>(bsum);
  scan3_k<<<NBLK, 256, 0, stream>>>(D, bsum);
  fill_k<<<3125, 256, 0, stream>>>(src, dst, eattr, D, csr); // D -> row ENDS

  // ---- fused layers (flat edge-walk gather inside), ping-pong h ----
  layerf_k<64,0><<<6250, 256, 0, stream>>>(h0,    D, csr, eb,        wb10, b10, wb20, b20, eps0, bufH);
  layerf_k<256,1><<<6250, 256, 0, stream>>>(bufH, D, csr, eb + 1024, wb11, b11, wb21, b21, eps1, hPong);
  layerf_k<256,1><<<6250, 256, 0, stream>>>(hPong,D, csr, eb + 2048, wb12, b12, wb22, b22, eps2, bufH);

  // ---- readout + MFMA head ----
  readout_k<<<GG, 256, 0, stream>>>(bufH, batch, x, sqlIds, sqlMask, tok, catb);
  head1_k<<<32, 256, 0, stream>>>(catb, mW1b, mb1, hidb);
  head2_k<<<dim3(16, 4), 256, 0, stream>>>(hidb, mW2b, mb2, out);
}

// Round 14
// 878.791 us; speedup vs baseline: 1.4467x; 1.4467x over previous
//
#include <hip/hip_runtime.h>

#define NN 200000
#define EE 800000
#define GG 2048
#define NBLK ((NN + 255) / 256)   // 782

typedef __attribute__((ext_vector_type(8))) short short8;
typedef __attribute__((ext_vector_type(4))) float f32x4;

__device__ __forceinline__ float bf2f(ushort u){
  unsigned x = ((unsigned)u) << 16;
  return __uint_as_float(x);
}
__device__ __forceinline__ ushort f2bf(float f){
  unsigned x = __float_as_uint(f);
  x += 0x7fffu + ((x >> 16) & 1u);
  return (ushort)(x >> 16);
}

// swizzle a 256xK fp32 weight into MFMA B-fragment order (K=256)
__device__ __forceinline__ void swz256(const float* __restrict__ W, ushort* __restrict__ o, int idx){
  int ks = idx >> 13, rem = idx & 8191;
  int j16 = rem >> 9, rem2 = rem & 511;
  int ln = rem2 >> 3, t = rem2 & 7;
  int row = j16*16 + (ln & 15);
  int k = ks*32 + (ln >> 4)*8 + t;
  o[idx] = f2bf(W[(size_t)row*256 + k]);
}

// ---------------- prep: weight conversion/swizzle + edge-bias tables ----------------
__global__ __launch_bounds__(256) void prep_k(
    const float* __restrict__ W10, const float* __restrict__ W20,
    const float* __restrict__ W11, const float* __restrict__ W21,
    const float* __restrict__ W12, const float* __restrict__ W22,
    const float* __restrict__ lw0, const float* __restrict__ lb0,
    const float* __restrict__ lw1, const float* __restrict__ lb1,
    const float* __restrict__ lw2, const float* __restrict__ lb2,
    const float* __restrict__ eE, const float* __restrict__ mW1,
    const float* __restrict__ mW2,
    ushort* __restrict__ wb10, ushort* __restrict__ wb20,
    ushort* __restrict__ wb11, ushort* __restrict__ wb21,
    ushort* __restrict__ wb12, ushort* __restrict__ wb22,
    ushort* __restrict__ mW1b, ushort* __restrict__ mW2b,
    float* __restrict__ eb)
{
  int b = blockIdx.x, tid = threadIdx.x;
  if (b < 64){ // W1_0 (256x44) -> B-frag swizzled 256x64 (2 kslices), zero-padded
    int idx = b*256 + tid;
    int ks = idx >> 13, rem = idx & 8191;
    int j16 = rem >> 9, rem2 = rem & 511;
    int ln = rem2 >> 3, t = rem2 & 7;
    int row = j16*16 + (ln & 15);
    int k = ks*32 + (ln >> 4)*8 + t;
    wb10[idx] = (k < 44) ? f2bf(W10[row*44 + k]) : (ushort)0;
    return;
  }
  b -= 64;
  if (b < 256){ swz256(W20, wb20, b*256+tid); return; } b -= 256;
  if (b < 256){ swz256(W11, wb11, b*256+tid); return; } b -= 256;
  if (b < 256){ swz256(W21, wb21, b*256+tid); return; } b -= 256;
  if (b < 256){ swz256(W12, wb12, b*256+tid); return; } b -= 256;
  if (b < 256){ swz256(W22, wb22, b*256+tid); return; } b -= 256;
  if (b < 384){ // mW1 (256x323) -> padded row-major (256x384)
    int idx = b*256 + tid; int o = idx / 384, k = idx - o*384;
    mW1b[idx] = (k < 323) ? f2bf(mW1[(size_t)o*323 + k]) : (ushort)0;
    return;
  }
  b -= 384;
  if (b < 512){ int idx = b*256+tid; mW2b[idx] = f2bf(mW2[idx]); return; } b -= 512;
  int li = b >> 2, t = b & 3;
  const float* lw = (li == 0) ? lw0 : ((li == 1) ? lw1 : lw2);
  const float* lb = (li == 0) ? lb0 : ((li == 1) ? lb1 : lb2);
  int d = (li == 0) ? 44 : 256;
  float v = 0.f;
  if (tid < d){
    float a = 0.f;
    #pragma unroll
    for (int j = 0; j < 16; j++) a += eE[t*16 + j] * lw[tid*16 + j];
    v = a + lb[tid];
  }
  eb[(li*4 + t)*256 + tid] = v;
}

// ---------------- h0 = [op_embed[op], nums, 0-pad] as bf16 N x 64 ----------------
__global__ __launch_bounds__(256) void build_h0_k(
    const float* __restrict__ x, const float* __restrict__ opE, ushort* __restrict__ h0)
{
  int idx = blockIdx.x*256 + threadIdx.x;
  int i = idx >> 6, c = idx & 63;
  float v = 0.f;
  if (c < 32){
    int op = (int)x[(size_t)i*13];
    op = op < 0 ? 0 : (op > 63 ? 63 : op);
    v = opE[op*32 + c];
  } else if (c < 44){
    v = x[(size_t)i*13 + (c - 31)];
  }
  h0[idx] = f2bf(v);
}

// ================= CSR build =================
__global__ __launch_bounds__(256) void deg_k(const int* __restrict__ dst, int* __restrict__ D){
  int e = blockIdx.x*256 + threadIdx.x;
  atomicAdd(&D[dst[e]], 1);
}
__global__ __launch_bounds__(256) void scan1_k(int* __restrict__ D, int* __restrict__ bsum){
  __shared__ int s[256];
  int b = blockIdx.x, t = threadIdx.x, idx = b*256 + t;
  int v = (idx < NN) ? D[idx] : 0;
  s[t] = v; __syncthreads();
  for (int off = 1; off < 256; off <<= 1){
    int u = (t >= off) ? s[t-off] : 0;
    __syncthreads();
    s[t] += u;
    __syncthreads();
  }
  if (idx < NN) D[idx] = s[t] - v;
  if (t == 255) bsum[b] = s[255];
}
__global__ __launch_bounds__(256) void scan2_k(int* __restrict__ bsum){
  __shared__ int s[256];
  __shared__ int carry;
  int t = threadIdx.x;
  if (t == 0) carry = 0;
  __syncthreads();
  for (int c0 = 0; c0 < NBLK; c0 += 256){
    int idx = c0 + t;
    int v = (idx < NBLK) ? bsum[idx] : 0;
    s[t] = v; __syncthreads();
    for (int off = 1; off < 256; off <<= 1){
      int u = (t >= off) ? s[t-off] : 0;
      __syncthreads();
      s[t] += u;
      __syncthreads();
    }
    int ex = s[t] - v + carry;
    if (idx < NBLK) bsum[idx] = ex;
    int tot = s[255];
    __syncthreads();
    if (t == 0) carry += tot;
    __syncthreads();
  }
}
__global__ __launch_bounds__(256) void scan3_k(int* __restrict__ D, const int* __restrict__ bsum){
  int b = blockIdx.x, idx = b*256 + threadIdx.x;
  if (idx < NN) D[idx] += bsum[b];
}
__global__ __launch_bounds__(256) void fill_k(const int* __restrict__ src, const int* __restrict__ dst,
                                              const int* __restrict__ et, int* __restrict__ D,
                                              int* __restrict__ csr){
  int e = blockIdx.x*256 + threadIdx.x;
  int d = dst[e];
  int t = et[e]; t = t < 3 ? t : 3;
  int pos = atomicAdd(&D[d], 1);
  csr[pos] = src[e] | (t << 18);
}

// ---------------- fused layer: gather + z + GEMM1 + GEMM2 + LN + resid + leaky ----------------
// 32 rows/block, grid 6250. Phase A: quad-row edge streams with DEPTH-2 prefetch
// (8 gathers in flight/wave), float4 eb reads, 32-bit byte-offset addressing.
// Residual re-reads global h (L2/L3-hot).
template<int KD, int RESID>
__global__ __launch_bounds__(256) void layerf_k(
    const ushort* __restrict__ hsrc, const int* __restrict__ Dend, const int* __restrict__ csr,
    const float* __restrict__ ebL,
    const ushort* __restrict__ W1s, const float* __restrict__ b1,
    const ushort* __restrict__ W2s, const float* __restrict__ b2,
    const float* __restrict__ epsp, ushort* __restrict__ hout)
{
  __shared__ ushort ZT[32][264];
  __shared__ float ebs[1024];
  __shared__ float red1[32][4], red2[32][4], mnL[32], rsL[32];
  const int tid = threadIdx.x, lane = tid & 63, wv = tid >> 6;
  const int l15 = lane & 15, lq = lane >> 4;
  const int rowBase = blockIdx.x * 32;
  const float epv = 1.0f + epsp[0];
  const char* hb = (const char*)hsrc;

  if (KD == 256){
    for (int i = tid; i < 1024; i += 256) ebs[i] = ebL[i];
  } else {
    if (tid < 256) ebs[tid] = ebL[(tid >> 6)*256 + (tid & 63)];  // compact [4][64]
  }
  __syncthreads();

  // ---- A: z = (1+eps)h[r] + sum_e relu(h[src]+eb[et]) -> ZT ----
  if (KD == 256){
    const int c = lane * 4;
    const unsigned cb = lane * 8;   // byte offset within row
    #pragma unroll 1
    for (int it = 0; it < 2; it++){
      int rr0 = wv*8 + it*4;
      int r0 = rowBase + rr0;
      float4 A0, A1, A2, A3;
      {
        ushort4 q0 = *(const ushort4*)(hb + (size_t)(r0+0)*512 + cb);
        ushort4 q1 = *(const ushort4*)(hb + (size_t)(r0+1)*512 + cb);
        ushort4 q2 = *(const ushort4*)(hb + (size_t)(r0+2)*512 + cb);
        ushort4 q3 = *(const ushort4*)(hb + (size_t)(r0+3)*512 + cb);
        A0 = make_float4(epv*bf2f(q0.x), epv*bf2f(q0.y), epv*bf2f(q0.z), epv*bf2f(q0.w));
        A1 = make_float4(epv*bf2f(q1.x), epv*bf2f(q1.y), epv*bf2f(q1.z), epv*bf2f(q1.w));
        A2 = make_float4(epv*bf2f(q2.x), epv*bf2f(q2.y), epv*bf2f(q2.z), epv*bf2f(q2.w));
        A3 = make_float4(epv*bf2f(q3.x), epv*bf2f(q3.y), epv*bf2f(q3.z), epv*bf2f(q3.w));
      }
      int bm1 = (r0 == 0) ? 0 : Dend[r0-1];
      int e0 = Dend[r0], e1 = Dend[r0+1], e2 = Dend[r0+2], e3 = Dend[r0+3];
      int st0 = bm1, st1 = e0, st2 = e1, st3 = e2;
      int n0 = e0 - st0, n1 = e1 - st1, n2 = e2 - st2, n3 = e3 - st3;
      int nmax = n0 > n1 ? n0 : n1;
      nmax = nmax > n2 ? nmax : n2;
      nmax = nmax > n3 ? nmax : n3;
      ushort4 z4; z4.x = z4.y = z4.z = z4.w = 0;
      // depth-2 slots: a* = even edges, b* = odd edges
      ushort4 a0 = z4, a1 = z4, a2 = z4, a3 = z4;
      ushort4 b0 = z4, b1 = z4, b2 = z4, b3 = z4;
      int ta0 = 0, ta1 = 0, ta2 = 0, ta3 = 0;
      int tb0 = 0, tb1 = 0, tb2 = 0, tb3 = 0;
      if (0 < n0){ int p = csr[st0]; a0 = *(const ushort4*)(hb + (unsigned)((p & 0x3FFFF) << 9) + cb); ta0 = ((p >> 18) & 3)*256; }
      if (0 < n1){ int p = csr[st1]; a1 = *(const ushort4*)(hb + (unsigned)((p & 0x3FFFF) << 9) + cb); ta1 = ((p >> 18) & 3)*256; }
      if (0 < n2){ int p = csr[st2]; a2 = *(const ushort4*)(hb + (unsigned)((p & 0x3FFFF) << 9) + cb); ta2 = ((p >> 18) & 3)*256; }
      if (0 < n3){ int p = csr[st3]; a3 = *(const ushort4*)(hb + (unsigned)((p & 0x3FFFF) << 9) + cb); ta3 = ((p >> 18) & 3)*256; }
      if (1 < n0){ int p = csr[st0+1]; b0 = *(const ushort4*)(hb + (unsigned)((p & 0x3FFFF) << 9) + cb); tb0 = ((p >> 18) & 3)*256; }
      if (1 < n1){ int p = csr[st1+1]; b1 = *(const ushort4*)(hb + (unsigned)((p & 0x3FFFF) << 9) + cb); tb1 = ((p >> 18) & 3)*256; }
      if (1 < n2){ int p = csr[st2+1]; b2 = *(const ushort4*)(hb + (unsigned)((p & 0x3FFFF) << 9) + cb); tb2 = ((p >> 18) & 3)*256; }
      if (1 < n3){ int p = csr[st3+1]; b3 = *(const ushort4*)(hb + (unsigned)((p & 0x3FFFF) << 9) + cb); tb3 = ((p >> 18) & 3)*256; }
      for (int k = 0; k < nmax; k += 2){
        // even edge k: consume slot a, refill with edge k+2
        if (k < n0){
          const float4 ev = *(const float4*)&ebs[ta0 + c];
          float v;
          v = bf2f(a0.x) + ev.x; A0.x += v > 0.f ? v : 0.f;
          v = bf2f(a0.y) + ev.y; A0.y += v > 0.f ? v : 0.f;
          v = bf2f(a0.z) + ev.z; A0.z += v > 0.f ? v : 0.f;
          v = bf2f(a0.w) + ev.w; A0.w += v > 0.f ? v : 0.f;
          if (k+2 < n0){ int p = csr[st0+k+2]; a0 = *(const ushort4*)(hb + (unsigned)((p & 0x3FFFF) << 9) + cb); ta0 = ((p >> 18) & 3)*256; }
        }
        if (k < n1){
          const float4 ev = *(const float4*)&ebs[ta1 + c];
          float v;
          v = bf2f(a1.x) + ev.x; A1.x += v > 0.f ? v : 0.f;
          v = bf2f(a1.y) + ev.y; A1.y += v > 0.f ? v : 0.f;
          v = bf2f(a1.z) + ev.z; A1.z += v > 0.f ? v : 0.f;
          v = bf2f(a1.w) + ev.w; A1.w += v > 0.f ? v : 0.f;
          if (k+2 < n1){ int p = csr[st1+k+2]; a1 = *(const ushort4*)(hb + (unsigned)((p & 0x3FFFF) << 9) + cb); ta1 = ((p >> 18) & 3)*256; }
        }
        if (k < n2){
          const float4 ev = *(const float4*)&ebs[ta2 + c];
          float v;
          v = bf2f(a2.x) + ev.x; A2.x += v > 0.f ? v : 0.f;
          v = bf2f(a2.y) + ev.y; A2.y += v > 0.f ? v : 0.f;
          v = bf2f(a2.z) + ev.z; A2.z += v > 0.f ? v : 0.f;
          v = bf2f(a2.w) + ev.w; A2.w += v > 0.f ? v : 0.f;
          if (k+2 < n2){ int p = csr[st2+k+2]; a2 = *(const ushort4*)(hb + (unsigned)((p & 0x3FFFF) << 9) + cb); ta2 = ((p >> 18) & 3)*256; }
        }
        if (k < n3){
          const float4 ev = *(const float4*)&ebs[ta3 + c];
          float v;
          v = bf2f(a3.x) + ev.x; A3.x += v > 0.f ? v : 0.f;
          v = bf2f(a3.y) + ev.y; A3.y += v > 0.f ? v : 0.f;
          v = bf2f(a3.z) + ev.z; A3.z += v > 0.f ? v : 0.f;
          v = bf2f(a3.w) + ev.w; A3.w += v > 0.f ? v : 0.f;
          if (k+2 < n3){ int p = csr[st3+k+2]; a3 = *(const ushort4*)(hb + (unsigned)((p & 0x3FFFF) << 9) + cb); ta3 = ((p >> 18) & 3)*256; }
        }
        // odd edge k+1: consume slot b, refill with edge k+3
        if (k+1 < n0){
          const float4 ev = *(const float4*)&ebs[tb0 + c];
          float v;
          v = bf2f(b0.x) + ev.x; A0.x += v > 0.f ? v : 0.f;
          v = bf2f(b0.y) + ev.y; A0.y += v > 0.f ? v : 0.f;
          v = bf2f(b0.z) + ev.z; A0.z += v > 0.f ? v : 0.f;
          v = bf2f(b0.w) + ev.w; A0.w += v > 0.f ? v : 0.f;
          if (k+3 < n0){ int p = csr[st0+k+3]; b0 = *(const ushort4*)(hb + (unsigned)((p & 0x3FFFF) << 9) + cb); tb0 = ((p >> 18) & 3)*256; }
        }
        if (k+1 < n1){
          const float4 ev = *(const float4*)&ebs[tb1 + c];
          float v;
          v = bf2f(b1.x) + ev.x; A1.x += v > 0.f ? v : 0.f;
          v = bf2f(b1.y) + ev.y; A1.y += v > 0.f ? v : 0.f;
          v = bf2f(b1.z) + ev.z; A1.z += v > 0.f ? v : 0.f;
          v = bf2f(b1.w) + ev.w; A1.w += v > 0.f ? v : 0.f;
          if (k+3 < n1){ int p = csr[st1+k+3]; b1 = *(const ushort4*)(hb + (unsigned)((p & 0x3FFFF) << 9) + cb); tb1 = ((p >> 18) & 3)*256; }
        }
        if (k+1 < n2){
          const float4 ev = *(const float4*)&ebs[tb2 + c];
          float v;
          v = bf2f(b2.x) + ev.x; A2.x += v > 0.f ? v : 0.f;
          v = bf2f(b2.y) + ev.y; A2.y += v > 0.f ? v : 0.f;
          v = bf2f(b2.z) + ev.z; A2.z += v > 0.f ? v : 0.f;
          v = bf2f(b2.w) + ev.w; A2.w += v > 0.f ? v : 0.f;
          if (k+3 < n2){ int p = csr[st2+k+3]; b2 = *(const ushort4*)(hb + (unsigned)((p & 0x3FFFF) << 9) + cb); tb2 = ((p >> 18) & 3)*256; }
        }
        if (k+1 < n3){
          const float4 ev = *(const float4*)&ebs[tb3 + c];
          float v;
          v = bf2f(b3.x) + ev.x; A3.x += v > 0.f ? v : 0.f;
          v = bf2f(b3.y) + ev.y; A3.y += v > 0.f ? v : 0.f;
          v = bf2f(b3.z) + ev.z; A3.z += v > 0.f ? v : 0.f;
          v = bf2f(b3.w) + ev.w; A3.w += v > 0.f ? v : 0.f;
          if (k+3 < n3){ int p = csr[st3+k+3]; b3 = *(const ushort4*)(hb + (unsigned)((p & 0x3FFFF) << 9) + cb); tb3 = ((p >> 18) & 3)*256; }
        }
      }
      ushort4 o;
      o.x = f2bf(A0.x); o.y = f2bf(A0.y); o.z = f2bf(A0.z); o.w = f2bf(A0.w);
      *(ushort4*)&ZT[rr0+0][c] = o;
      o.x = f2bf(A1.x); o.y = f2bf(A1.y); o.z = f2bf(A1.z); o.w = f2bf(A1.w);
      *(ushort4*)&ZT[rr0+1][c] = o;
      o.x = f2bf(A2.x); o.y = f2bf(A2.y); o.z = f2bf(A2.z); o.w = f2bf(A2.w);
      *(ushort4*)&ZT[rr0+2][c] = o;
      o.x = f2bf(A3.x); o.y = f2bf(A3.y); o.z = f2bf(A3.z); o.w = f2bf(A3.w);
      *(ushort4*)&ZT[rr0+3][c] = o;
    }
  } else {
    const int c = l15 * 4;
    const unsigned c2 = l15 * 8;
    #pragma unroll 1
    for (int it = 0; it < 2; it++){
      int rr = wv*8 + it*4 + lq;
      int r = rowBase + rr;
      const ushort4 hv = *(const ushort4*)(hb + (size_t)r*128 + c2);
      float a0 = epv*bf2f(hv.x), a1 = epv*bf2f(hv.y), a2 = epv*bf2f(hv.z), a3 = epv*bf2f(hv.w);
      int st = (r == 0) ? 0 : Dend[r-1];
      int en = Dend[r];
      if (st < en){
        int p = csr[st];
        ushort4 sv = *(const ushort4*)(hb + (unsigned)((p & 0x3FFFF) << 7) + c2);
        int tt = ((p >> 18) & 3)*64;
        for (int e = st; e < en; e++){
          ushort4 cur = sv; int tc = tt;
          int e2 = (e+1 < en) ? e+1 : e;
          int p2 = csr[e2];
          sv = *(const ushort4*)(hb + (unsigned)((p2 & 0x3FFFF) << 7) + c2);
          tt = ((p2 >> 18) & 3)*64;
          const float4 ev = *(const float4*)&ebs[tc + c];
          float v;
          v = bf2f(cur.x) + ev.x; a0 += v > 0.f ? v : 0.f;
          v = bf2f(cur.y) + ev.y; a1 += v > 0.f ? v : 0.f;
          v = bf2f(cur.z) + ev.z; a2 += v > 0.f ? v : 0.f;
          v = bf2f(cur.w) + ev.w; a3 += v > 0.f ? v : 0.f;
        }
      }
      ushort4 o; o.x=f2bf(a0); o.y=f2bf(a1); o.z=f2bf(a2); o.w=f2bf(a3);
      *(ushort4*)&ZT[rr][c] = o;
    }
  }
  __syncthreads();

  // ---- B: t = relu(z @ W1^T + b1), wave tile 32x64 ----
  f32x4 acc[2][4];
  #pragma unroll
  for (int i = 0; i < 2; i++)
    #pragma unroll
    for (int j = 0; j < 4; j++){ f32x4 z = {0.f,0.f,0.f,0.f}; acc[i][j] = z; }

  #pragma unroll
  for (int s = 0; s < KD/32; s++){
    short8 af[2], bfv[4];
    #pragma unroll
    for (int j = 0; j < 4; j++)
      bfv[j] = *(const short8*)(W1s + ((size_t)(s*16 + wv*4 + j)*64 + lane)*8);
    #pragma unroll
    for (int i = 0; i < 2; i++)
      af[i] = *(const short8*)&ZT[i*16 + l15][s*32 + lq*8];
    #pragma unroll
    for (int i = 0; i < 2; i++)
      #pragma unroll
      for (int j = 0; j < 4; j++)
        acc[i][j] = __builtin_amdgcn_mfma_f32_16x16x32_bf16(af[i], bfv[j], acc[i][j], 0, 0, 0);
  }
  __syncthreads();

  // ---- C: t -> ZT ----
  {
    float b1c[4];
    #pragma unroll
    for (int j = 0; j < 4; j++) b1c[j] = b1[wv*64 + j*16 + l15];
    #pragma unroll
    for (int i = 0; i < 2; i++)
      #pragma unroll
      for (int j = 0; j < 4; j++){
        int cc = wv*64 + j*16 + l15;
        #pragma unroll
        for (int rg = 0; rg < 4; rg++){
          int r = i*16 + (lq << 2) + rg;
          float v = acc[i][j][rg] + b1c[j];
          v = v > 0.f ? v : 0.f;
          ZT[r][cc] = f2bf(v);
        }
      }
  }
  __syncthreads();

  // ---- D: y = t @ W2^T ----
  #pragma unroll
  for (int i = 0; i < 2; i++)
    #pragma unroll
    for (int j = 0; j < 4; j++){ f32x4 z = {0.f,0.f,0.f,0.f}; acc[i][j] = z; }

  #pragma unroll
  for (int s = 0; s < 8; s++){
    short8 af[2], bfv[4];
    #pragma unroll
    for (int j = 0; j < 4; j++)
      bfv[j] = *(const short8*)(W2s + ((size_t)(s*16 + wv*4 + j)*64 + lane)*8);
    #pragma unroll
    for (int i = 0; i < 2; i++)
      af[i] = *(const short8*)&ZT[i*16 + l15][s*32 + lq*8];
    #pragma unroll
    for (int i = 0; i < 2; i++)
      #pragma unroll
      for (int j = 0; j < 4; j++)
        acc[i][j] = __builtin_amdgcn_mfma_f32_16x16x32_bf16(af[i], bfv[j], acc[i][j], 0, 0, 0);
  }

  // ---- E: LayerNorm stats ----
  float b2c[4];
  #pragma unroll
  for (int j = 0; j < 4; j++) b2c[j] = b2[wv*64 + j*16 + l15];
  #pragma unroll
  for (int i = 0; i < 2; i++){
    #pragma unroll
    for (int rg = 0; rg < 4; rg++){
      float s1 = 0.f, s2 = 0.f;
      #pragma unroll
      for (int j = 0; j < 4; j++){
        float y = acc[i][j][rg] + b2c[j];
        s1 += y; s2 += y*y;
      }
      #pragma unroll
      for (int m = 1; m < 16; m <<= 1){
        s1 += __shfl_xor(s1, m, 64);
        s2 += __shfl_xor(s2, m, 64);
      }
      if (l15 == 0){
        int r = i*16 + (lq << 2) + rg;
        red1[r][wv] = s1; red2[r][wv] = s2;
      }
    }
  }
  __syncthreads();
  if (tid < 32){
    float s1 = red1[tid][0] + red1[tid][1] + red1[tid][2] + red1[tid][3];
    float s2 = red2[tid][0] + red2[tid][1] + red2[tid][2] + red2[tid][3];
    float mn = s1 * (1.f/256.f);
    float vr = s2 * (1.f/256.f) - mn*mn;
    mnL[tid] = mn;
    rsL[tid] = rsqrtf(vr + 1e-5f);
  }
  __syncthreads();
  // ---- F: LN + resid (global re-read, L2/L3-hot) + leaky -> ZT ----
  #pragma unroll
  for (int i = 0; i < 2; i++){
    #pragma unroll
    for (int rg = 0; rg < 4; rg++){
      int r = i*16 + (lq << 2) + rg;
      float mn = mnL[r], rs = rsL[r];
      #pragma unroll
      for (int j = 0; j < 4; j++){
        int cc = wv*64 + j*16 + l15;
        float y = acc[i][j][rg] + b2c[j];
        float v = (y - mn) * rs;
        if (RESID) v += bf2f(hsrc[(size_t)(rowBase + r)*256 + cc]);
        v = v > 0.f ? v : 0.1f*v;
        ZT[r][cc] = f2bf(v);
      }
    }
  }
  __syncthreads();
  // ---- G: coalesced store ----
  #pragma unroll
  for (int p = 0; p < 8; p++){
    int r = p*4 + (tid >> 6);
    int c = (tid & 63) * 4;
    *(ushort4*)(hout + (size_t)(rowBase + r)*256 + c) = *(const ushort4*)&ZT[r][c];
  }
}

// ---------------- readout -> catb bf16 (G x 384); row-parallel waves ----------------
__global__ __launch_bounds__(256) void readout_k(
    const ushort* __restrict__ h, const int* __restrict__ batch, const float* __restrict__ x,
    const int* __restrict__ sqlIds, const float* __restrict__ sqlMask,
    const float* __restrict__ tok, ushort* __restrict__ catb)
{
  int g = blockIdx.x, tid = threadIdx.x;
  const int lane = tid & 63, wv = tid >> 6;
  __shared__ int se[2];
  __shared__ float part[4][256];
  __shared__ float tpart[4][64];
  __shared__ float mpart[4];
  __shared__ float xs[2];
  if (tid < 2){
    int target = g + tid;
    int lo = 0, hi = NN;
    while (lo < hi){ int mid = (lo + hi) >> 1; if (batch[mid] < target) lo = mid + 1; else hi = mid; }
    se[tid] = lo;
  }
  __syncthreads();
  int start = se[0], end = se[1];
  {
    float a0 = 0.f, a1 = 0.f, a2 = 0.f, a3 = 0.f;
    for (int i = start + wv; i < end; i += 4){
      ushort4 q = *(const ushort4*)(h + (size_t)i*256 + lane*4);
      a0 += bf2f(q.x); a1 += bf2f(q.y); a2 += bf2f(q.z); a3 += bf2f(q.w);
    }
    part[wv][lane*4 + 0] = a0;
    part[wv][lane*4 + 1] = a1;
    part[wv][lane*4 + 2] = a2;
    part[wv][lane*4 + 3] = a3;
  }
  if (wv >= 2){
    int col = (wv == 2) ? 5 : 4;
    float s = 0.f;
    for (int i = start + lane; i < end; i += 64) s += x[(size_t)i*13 + col];
    #pragma unroll
    for (int m = 1; m < 64; m <<= 1) s += __shfl_xor(s, m, 64);
    if (lane == 0) xs[wv - 2] = s;
  }
  {
    int c = lane;
    float acc = 0.f, m = 0.f;
    for (int s = wv; s < 128; s += 4){
      int id = sqlIds[g*128 + s];
      float mk = sqlMask[g*128 + s];
      m += mk;
      acc += tok[(size_t)id*64 + c] * mk;
    }
    tpart[wv][c] = acc;
    if (c == 0) mpart[wv] = m;
  }
  __syncthreads();
  {
    float gsum = part[0][tid] + part[1][tid] + part[2][tid] + part[3][tid];
    catb[(size_t)g*384 + tid] = f2bf(gsum);
  }
  if (tid == 0){
    float cnt = (float)(end - start);
    float dn = cnt > 1.f ? cnt : 1.f;
    catb[(size_t)g*384 + 256] = f2bf(cnt);
    catb[(size_t)g*384 + 257] = f2bf(xs[0] / dn);
    catb[(size_t)g*384 + 258] = f2bf(xs[1] / dn);
  }
  if (tid < 64){
    float L = mpart[0] + mpart[1] + mpart[2] + mpart[3];
    L = L > 1.f ? L : 1.f;
    float tsum = tpart[0][tid] + tpart[1][tid] + tpart[2][tid] + tpart[3][tid];
    catb[(size_t)g*384 + 259 + tid] = f2bf(tsum / L);
  }
  if (tid >= 64 && tid < 125){
    catb[(size_t)g*384 + 259 + tid] = 0;   // zero pad 323..383
  }
}

// ---------------- head GEMM1: hid = leaky(catb @ mW1b^T + mb1), bf16 out ----------------
__global__ __launch_bounds__(256) void head1_k(
    const ushort* __restrict__ catb, const ushort* __restrict__ W1b,
    const float* __restrict__ b1, ushort* __restrict__ hidb)
{
  __shared__ ushort smem[64*72 + 256*72];
  ushort (*As)[72] = (ushort(*)[72])smem;
  ushort (*Ws)[72] = (ushort(*)[72])(smem + 64*72);
  const int tid = threadIdx.x, lane = tid & 63, wv = tid >> 6;
  const int rowBase = blockIdx.x * 64;
  f32x4 acc[4][4];
  #pragma unroll
  for (int i = 0; i < 4; i++)
    #pragma unroll
    for (int j = 0; j < 4; j++){ f32x4 z = {0.f,0.f,0.f,0.f}; acc[i][j] = z; }

  for (int k0 = 0; k0 < 384; k0 += 64){
    __syncthreads();
    #pragma unroll
    for (int p = 0; p < 4; p++){
      int r = p*16 + (tid >> 4);
      int kk = (tid & 15) * 4;
      *(ushort4*)&As[r][kk] = *(const ushort4*)(catb + (size_t)(rowBase + r)*384 + k0 + kk);
    }
    #pragma unroll
    for (int p = 0; p < 16; p++){
      int oc = p*16 + (tid >> 4);
      int kk = (tid & 15) * 4;
      *(ushort4*)&Ws[oc][kk] = *(const ushort4*)(W1b + (size_t)oc*384 + k0 + kk);
    }
    __syncthreads();
    #pragma unroll
    for (int kc = 0; kc < 2; kc++){
      short8 af[4], bfv[4];
      #pragma unroll
      for (int i = 0; i < 4; i++)
        af[i] = *(const short8*)&As[i*16 + (lane & 15)][kc*32 + (lane >> 4)*8];
      #pragma unroll
      for (int j = 0; j < 4; j++)
        bfv[j] = *(const short8*)&Ws[wv*64 + j*16 + (lane & 15)][kc*32 + (lane >> 4)*8];
      #pragma unroll
      for (int i = 0; i < 4; i++)
        #pragma unroll
        for (int j = 0; j < 4; j++)
          acc[i][j] = __builtin_amdgcn_mfma_f32_16x16x32_bf16(af[i], bfv[j], acc[i][j], 0, 0, 0);
    }
  }
  __syncthreads();
  ushort (*Cs)[264] = (ushort(*)[264])smem;
  #pragma unroll
  for (int j = 0; j < 4; j++){
    int cc = wv*64 + j*16 + (lane & 15);
    float bb = b1[cc];
    #pragma unroll
    for (int i = 0; i < 4; i++){
      #pragma unroll
      for (int rg = 0; rg < 4; rg++){
        int r = i*16 + ((lane >> 4) << 2) + rg;
        float v = acc[i][j][rg] + bb;
        v = v > 0.f ? v : 0.1f*v;
        Cs[r][cc] = f2bf(v);
      }
    }
  }
  __syncthreads();
  #pragma unroll
  for (int p = 0; p < 16; p++){
    int r = p*4 + (tid >> 6);
    int c = (tid & 63) * 4;
    *(ushort4*)(hidb + (size_t)(rowBase + r)*256 + c) = *(const ushort4*)&Cs[r][c];
  }
}

// ---------------- head GEMM2: out = hidb @ mW2b^T + mb2, fp32 out ----------------
__global__ __launch_bounds__(256) void head2_k(
    const ushort* __restrict__ hidb, const ushort* __restrict__ W2b,
    const float* __restrict__ b2, float* __restrict__ out)
{
  __shared__ float smemf[128*132];
  ushort (*As)[72] = (ushort(*)[72])smemf;
  ushort (*Bs)[72] = (ushort(*)[72])((ushort*)smemf + 128*72);
  const int tid = threadIdx.x, lane = tid & 63, wv = tid >> 6;
  const int wr = (wv >> 1) * 64;
  const int wc = (wv & 1) * 64;
  const int rowBase = blockIdx.x * 128;
  const int colBase = blockIdx.y * 128;
  const int lr = tid >> 4, lk = (tid & 15) * 4;

  f32x4 acc[4][4];
  #pragma unroll
  for (int i = 0; i < 4; i++)
    #pragma unroll
    for (int j = 0; j < 4; j++){ f32x4 z = {0.f,0.f,0.f,0.f}; acc[i][j] = z; }

  for (int k0 = 0; k0 < 256; k0 += 64){
    __syncthreads();
    #pragma unroll
    for (int p = 0; p < 8; p++){
      int r = lr + p*16;
      *(ushort4*)&As[r][lk] = *(const ushort4*)(hidb + (size_t)(rowBase + r)*256 + k0 + lk);
      *(ushort4*)&Bs[r][lk] = *(const ushort4*)(W2b + (size_t)(colBase + r)*256 + k0 + lk);
    }
    __syncthreads();
    #pragma unroll
    for (int kc = 0; kc < 2; kc++){
      short8 af[4], bfv[4];
      #pragma unroll
      for (int i = 0; i < 4; i++)
        af[i] = *(const short8*)&As[wr + i*16 + (lane & 15)][kc*32 + (lane >> 4)*8];
      #pragma unroll
      for (int j = 0; j < 4; j++)
        bfv[j] = *(const short8*)&Bs[wc + j*16 + (lane & 15)][kc*32 + (lane >> 4)*8];
      #pragma unroll
      for (int i = 0; i < 4; i++)
        #pragma unroll
        for (int j = 0; j < 4; j++)
          acc[i][j] = __builtin_amdgcn_mfma_f32_16x16x32_bf16(af[i], bfv[j], acc[i][j], 0, 0, 0);
    }
  }
  __syncthreads();
  float (*Cs)[132] = (float(*)[132])smemf;
  #pragma unroll
  for (int j = 0; j < 4; j++){
    int cl = wc + j*16 + (lane & 15);
    float bb = b2[colBase + cl];
    #pragma unroll
    for (int i = 0; i < 4; i++){
      int r0 = wr + i*16 + ((lane >> 4) << 2);
      #pragma unroll
      for (int rg = 0; rg < 4; rg++)
        Cs[r0 + rg][cl] = acc[i][j][rg] + bb;
    }
  }
  __syncthreads();
  #pragma unroll
  for (int p = 0; p < 16; p++){
    int r = (tid >> 5) + p*8;
    int c4 = (tid & 31) * 4;
    *(float4*)(out + (size_t)(rowBase + r)*512 + colBase + c4) = *(const float4*)&Cs[r][c4];
  }
}

extern "C" void kernel_launch(void* const* d_in, const int* in_sizes, int n_in,
                              void* d_out, int out_size, void* d_ws, size_t ws_size,
                              hipStream_t stream)
{
  const float* x       = (const float*)d_in[0];
  const int*   ei      = (const int*)d_in[1];
  const int*   src     = ei;
  const int*   dst     = ei + EE;
  const int*   eattr   = (const int*)d_in[2];
  const int*   batch   = (const int*)d_in[3];
  const int*   sqlIds  = (const int*)d_in[4];
  const float* sqlMask = (const float*)d_in[5];
  const float* opE     = (const float*)d_in[6];
  const float* eE      = (const float*)d_in[7];
  const float* tok     = (const float*)d_in[8];
  const float* lw0 = (const float*)d_in[9],  *lb0 = (const float*)d_in[10], *eps0 = (const float*)d_in[11];
  const float* W10 = (const float*)d_in[12], *b10 = (const float*)d_in[13];
  const float* W20 = (const float*)d_in[14], *b20 = (const float*)d_in[15];
  const float* lw1 = (const float*)d_in[16], *lb1 = (const float*)d_in[17], *eps1 = (const float*)d_in[18];
  const float* W11 = (const float*)d_in[19], *b11 = (const float*)d_in[20];
  const float* W21 = (const float*)d_in[21], *b21 = (const float*)d_in[22];
  const float* lw2 = (const float*)d_in[23], *lb2 = (const float*)d_in[24], *eps2 = (const float*)d_in[25];
  const float* W12 = (const float*)d_in[26], *b12 = (const float*)d_in[27];
  const float* W22 = (const float*)d_in[28], *b22 = (const float*)d_in[29];
  const float* mW1 = (const float*)d_in[30], *mb1 = (const float*)d_in[31];
  const float* mW2 = (const float*)d_in[32], *mb2 = (const float*)d_in[33];
  float* out = (float*)d_out;

  // ---- workspace layout (same footprint as R11) ----
  char* ws = (char*)d_ws;
  size_t off = 0;
  const size_t NB256 = (size_t)NN*256*2;
  ushort* bufH    = (ushort*)(ws + off); off += NB256;   // h ping buffer
  char*   region  = ws + off;            off += NB256;   // h0 / h pong buffer / catb+hidb
  ushort* h0      = (ushort*)region;
  ushort* hPong   = (ushort*)region;
  ushort* catb    = (ushort*)region;
  ushort* hidb    = (ushort*)(region + (size_t)GG*384*2);
  ushort* wb10 = (ushort*)(ws + off); off += (size_t)256*64*2;
  ushort* wb20 = (ushort*)(ws + off); off += (size_t)65536*2;
  ushort* wb11 = (ushort*)(ws + off); off += (size_t)65536*2;
  ushort* wb21 = (ushort*)(ws + off); off += (size_t)65536*2;
  ushort* wb12 = (ushort*)(ws + off); off += (size_t)65536*2;
  ushort* wb22 = (ushort*)(ws + off); off += (size_t)65536*2;
  ushort* mW1b = (ushort*)(ws + off); off += (size_t)256*384*2;
  ushort* mW2b = (ushort*)(ws + off); off += (size_t)512*256*2;
  float*  eb   = (float*)(ws + off);  off += (size_t)3*4*256*4;
  int* D    = (int*)(ws + off); off += (size_t)NN*4;
  int* bsum = (int*)(ws + off); off += (size_t)NBLK*4;
  int* csr  = (int*)(ws + off); off += (size_t)EE*4;
  size_t needFast = off;

  if (ws_size < needFast) return;

  prep_k<<<2252, 256, 0, stream>>>(W10, W20, W11, W21, W12, W22,
                                   lw0, lb0, lw1, lb1, lw2, lb2, eE, mW1, mW2,
                                   wb10, wb20, wb11, wb21, wb12, wb22, mW1b, mW2b, eb);
  build_h0_k<<<50000, 256, 0, stream>>>(x, opE, h0);

  // ---- CSR build (by dst) ----
  hipMemsetAsync(D, 0, (size_t)NN*4, stream);
  deg_k<<<3125, 256, 0, stream>>>(dst, D);
  scan1_k<<<NBLK, 256, 0, stream>>>(D, bsum);
  scan2_k<<<1, 256, 0, stream>>>(bsum);
  scan3_k<<<NBLK, 256, 0, stream>>>(D, bsum);
  fill_k<<<3125, 256, 0, stream>>>(src, dst, eattr, D, csr); // D -> row ENDS

  // ---- fused layers (gather inside), ping-pong h ----
  layerf_k<64,0><<<6250, 256, 0, stream>>>(h0,    D, csr, eb,        wb10, b10, wb20, b20, eps0, bufH);
  layerf_k<256,1><<<6250, 256, 0, stream>>>(bufH, D, csr, eb + 1024, wb11, b11, wb21, b21, eps1, hPong);
  layerf_k<256,1><<<6250, 256, 0, stream>>>(hPong,D, csr, eb + 2048, wb12, b12, wb22, b22, eps2, bufH);

  // ---- readout + MFMA head ----
  readout_k<<<GG, 256, 0, stream>>>(bufH, batch, x, sqlIds, sqlMask, tok, catb);
  head1_k<<<32, 256, 0, stream>>>(catb, mW1b, mb1, hidb);
  head2_k<<<dim3(16, 4), 256, 0, stream>>>(hidb, mW2b, mb2, out);
}